// Round 6
// baseline (356.250 us; speedup 1.0000x reference)
//
#include <hip/hip_runtime.h>

#define NN 100000
#define EE 1600000
#define DIN 128
#define DH 64
#define DOUT 32

#define BSH 8                      // bucket = dst >> 8  (256 nodes/bucket)
#define BNODES 256
#define NBUCK ((NN + BNODES - 1) / BNODES)   // 391
#define CHUNK 4096                 // edges per Pass-A workgroup
#define NCHUNK ((EE + CHUNK - 1) / CHUNK)    // 391

typedef unsigned short ush;

__device__ __forceinline__ float bf2f(ush u) {
    union { unsigned u; float f; } c; c.u = ((unsigned)u) << 16; return c.f;
}
__device__ __forceinline__ ush f2bf(float f) {
    union { float f; unsigned u; } c; c.f = f;
    unsigned r = c.u + 0x7fff + ((c.u >> 16) & 1);   // round-to-nearest-even
    return (ush)(r >> 16);
}

// ---------------- zero bucket counters ----------------
__global__ void zero_bcnt_kernel(int* __restrict__ bcnt) {
    int i = blockIdx.x * 256 + threadIdx.x;
    if (i < NBUCK) bcnt[i] = 0;
}

// ---------------- bucket histogram (LDS-first) ----------------
__global__ __launch_bounds__(256) void bhist_kernel(const int* __restrict__ dst,
                                                    int* __restrict__ bcnt) {
    __shared__ int h[NBUCK];
    int t = threadIdx.x;
    for (int i = t; i < NBUCK; i += 256) h[i] = 0;
    __syncthreads();
    int base = blockIdx.x * CHUNK;
    int end = min(base + CHUNK, EE);
    for (int i = base + t; i < end; i += 256) atomicAdd(&h[dst[i] >> BSH], 1);
    __syncthreads();
    for (int i = t; i < NBUCK; i += 256) if (h[i]) atomicAdd(&bcnt[i], h[i]);
}

// ---------------- bucket exclusive scan (1 wg) ----------------
__global__ __launch_bounds__(256) void bscan_kernel(const int* __restrict__ bcnt,
                                                    int* __restrict__ bbase,
                                                    int* __restrict__ bcur,
                                                    int* __restrict__ offsets) {
    __shared__ int s2[256];
    int t = threadIdx.x;
    int a0 = (2 * t < NBUCK) ? bcnt[2 * t] : 0;
    int a1 = (2 * t + 1 < NBUCK) ? bcnt[2 * t + 1] : 0;
    s2[t] = a0 + a1;
    __syncthreads();
    for (int off = 1; off < 256; off <<= 1) {
        int x = (t >= off) ? s2[t - off] : 0;
        __syncthreads();
        s2[t] += x;
        __syncthreads();
    }
    int excl = s2[t] - a0 - a1;
    if (2 * t < NBUCK)     { bbase[2 * t] = excl;          bcur[2 * t] = excl; }
    if (2 * t + 1 < NBUCK) { bbase[2 * t + 1] = excl + a0; bcur[2 * t + 1] = excl + a0; }
    if (t == 255) { bbase[NBUCK] = s2[255]; offsets[NN] = s2[255]; }  // = EE
}

// ---------------- Pass A: bin edges into bucket-grouped tmp (packed (src<<8)|dstlow) ----
__global__ __launch_bounds__(256) void binA_kernel(const int* __restrict__ src,
                                                   const int* __restrict__ dst,
                                                   int* __restrict__ bcur,
                                                   unsigned* __restrict__ tmp) {
    __shared__ int hist[NBUCK];
    __shared__ int scn[NBUCK + 1];
    __shared__ int cur[NBUCK];
    __shared__ int gbase[NBUCK];
    __shared__ int s2[256];
    __shared__ unsigned staged[CHUNK];
    int t = threadIdx.x;
    for (int i = t; i < NBUCK; i += 256) hist[i] = 0;
    __syncthreads();
    int e0 = blockIdx.x * CHUNK;
    int nE = min(CHUNK, EE - e0);

    int my_e[16], my_bk[16];
#pragma unroll
    for (int k = 0; k < 16; k++) {
        int li = t + k * 256;
        bool ok = li < nE;
        int idx = ok ? (e0 + li) : e0;
        int d = dst[idx];
        int s = src[idx];
        int b = d >> BSH;
        my_e[k] = (s << 8) | (d & 255);
        my_bk[k] = ok ? b : -1;
        if (ok) atomicAdd(&hist[b], 1);
    }
    __syncthreads();
    int a0 = (2 * t < NBUCK) ? hist[2 * t] : 0;
    int a1 = (2 * t + 1 < NBUCK) ? hist[2 * t + 1] : 0;
    s2[t] = a0 + a1;
    __syncthreads();
    for (int off = 1; off < 256; off <<= 1) {
        int x = (t >= off) ? s2[t - off] : 0;
        __syncthreads();
        s2[t] += x;
        __syncthreads();
    }
    int excl = s2[t] - a0 - a1;
    if (2 * t < NBUCK)     { scn[2 * t] = excl;          cur[2 * t] = excl; }
    if (2 * t + 1 < NBUCK) { scn[2 * t + 1] = excl + a0; cur[2 * t + 1] = excl + a0; }
    if (t == 0) scn[NBUCK] = nE;
    __syncthreads();
    for (int i = t; i < NBUCK; i += 256)
        gbase[i] = hist[i] ? atomicAdd(&bcur[i], hist[i]) : 0;
    __syncthreads();
#pragma unroll
    for (int k = 0; k < 16; k++) {
        if (my_bk[k] >= 0) {
            int lp = atomicAdd(&cur[my_bk[k]], 1);
            staged[lp] = (unsigned)my_e[k];
        }
    }
    __syncthreads();
    for (int i = t; i < nE; i += 256) {
        int lo = 0, hi = NBUCK;
#pragma unroll
        for (int step = 0; step < 9; step++) {
            int mid = (lo + hi) >> 1;
            bool c = scn[mid] <= i;
            lo = c ? mid : lo;
            hi = c ? hi : mid;
        }
        tmp[gbase[lo] + (i - scn[lo])] = staged[i];
    }
}

// ---------------- Pass B: per-bucket node histogram + scan -> offsets/dinv/csr ----------
__global__ __launch_bounds__(256) void binB_kernel(const unsigned* __restrict__ tmp,
                                                   const int* __restrict__ bbase,
                                                   int* __restrict__ csr,
                                                   int* __restrict__ offsets,
                                                   float* __restrict__ dinv) {
    __shared__ int hist[BNODES], cur[BNODES], sc[BNODES];
    int b = blockIdx.x, t = threadIdx.x;
    int e0 = bbase[b], e1 = bbase[b + 1];
    hist[t] = 0;
    __syncthreads();
    for (int i = e0 + t; i < e1; i += 256) atomicAdd(&hist[tmp[i] & 255], 1);
    __syncthreads();
    int v = hist[t];
    sc[t] = v;
    __syncthreads();
    for (int off = 1; off < 256; off <<= 1) {
        int x = (t >= off) ? sc[t - off] : 0;
        __syncthreads();
        sc[t] += x;
        __syncthreads();
    }
    int excl = sc[t] - v;
    cur[t] = e0 + excl;
    int node = (b << BSH) + t;
    if (node < NN) {
        offsets[node] = e0 + excl;
        dinv[node] = 1.0f / sqrtf((float)v + 1.0f);
    }
    __syncthreads();
    for (int i = e0 + t; i < e1; i += 256) {
        unsigned u = tmp[i];
        int pos = atomicAdd(&cur[u & 255], 1);
        csr[pos] = (int)(u >> 8);
    }
}

// ---------------- GEMM1 + dinv-scale, bf16 out: Hs1[r,:] = bf16((X[r,:]@W1) * dinv[r]) --
// 256 threads; each thread computes 4 rows x 4 cols. X tile padded in LDS.
template <int K, int NC>
__global__ __launch_bounds__(256) void gemm_bf_kernel(const float* __restrict__ X,
                                                      const float* __restrict__ W,
                                                      const float* __restrict__ dinv,
                                                      ush* __restrict__ Y) {
    constexpr int CG   = NC / 4;
    constexpr int RS   = 256 / CG;
    constexpr int ROWS = RS * 4;
    constexpr int XP   = K + 4;
    __shared__ float Wl[K * NC];
    __shared__ float Xl[ROWS * XP];
    const int t = threadIdx.x;
    const int row0 = blockIdx.x * ROWS;

    for (int i = t; i < K * (NC / 4); i += 256) {
        int k = i / (NC / 4), c = i % (NC / 4);
        *(float4*)&Wl[k * NC + c * 4] = *(const float4*)&W[k * NC + c * 4];
    }
    for (int i = t; i < ROWS * (K / 4); i += 256) {
        int r = i / (K / 4), c = i % (K / 4);
        float4 v = make_float4(0.f, 0.f, 0.f, 0.f);
        if (row0 + r < NN) v = *(const float4*)&X[(row0 + r) * K + c * 4];
        *(float4*)&Xl[r * XP + c * 4] = v;
    }
    __syncthreads();

    const int cg = t & (CG - 1);
    const int rs = t / CG;
    float4 acc[4];
#pragma unroll
    for (int rr = 0; rr < 4; rr++) acc[rr] = make_float4(0.f, 0.f, 0.f, 0.f);

#pragma unroll 4
    for (int k = 0; k < K; k += 4) {
        float4 w0 = *(const float4*)&Wl[(k + 0) * NC + cg * 4];
        float4 w1 = *(const float4*)&Wl[(k + 1) * NC + cg * 4];
        float4 w2 = *(const float4*)&Wl[(k + 2) * NC + cg * 4];
        float4 w3 = *(const float4*)&Wl[(k + 3) * NC + cg * 4];
#pragma unroll
        for (int rr = 0; rr < 4; rr++) {
            float4 xv = *(const float4*)&Xl[(rs * 4 + rr) * XP + k];
            acc[rr].x += xv.x * w0.x + xv.y * w1.x + xv.z * w2.x + xv.w * w3.x;
            acc[rr].y += xv.x * w0.y + xv.y * w1.y + xv.z * w2.y + xv.w * w3.y;
            acc[rr].z += xv.x * w0.z + xv.y * w1.z + xv.z * w2.z + xv.w * w3.z;
            acc[rr].w += xv.x * w0.w + xv.y * w1.w + xv.z * w2.w + xv.w * w3.w;
        }
    }
#pragma unroll
    for (int rr = 0; rr < 4; rr++) {
        int row = row0 + rs * 4 + rr;
        if (row < NN) {
            float s = dinv[row];
            ushort4 o;
            o.x = f2bf(acc[rr].x * s); o.y = f2bf(acc[rr].y * s);
            o.z = f2bf(acc[rr].z * s); o.w = f2bf(acc[rr].w * s);
            *(ushort4*)&Y[row * NC + cg * 4] = o;
        }
    }
}

// ---------------- gather1 + fused GEMM2: wave/node, 4 edge-slots x 16 fgroups --------
// h1 = relu(dv*(sum Hs1[s] + Hs1[node]) + b1)  (kept in regs, row across 16 lanes)
// Hs2[node,:] = bf16((h1 @ W2) * dv)
__global__ __launch_bounds__(256) void gather1_kernel(const int* __restrict__ offsets,
                                                      const int* __restrict__ csr,
                                                      const float* __restrict__ dinv,
                                                      const ush* __restrict__ Hs,
                                                      const float* __restrict__ b1,
                                                      const float* __restrict__ W2,
                                                      ush* __restrict__ Hs2) {
    __shared__ float W2T[DOUT * DH];   // transposed: W2T[c*64+k] = W2[k*32+c]
    int t = threadIdx.x;
    for (int i = t; i < DH * DOUT; i += 256) {
        int k = i >> 5, c = i & 31;
        W2T[c * DH + k] = W2[i];
    }
    __syncthreads();
    int node = (blockIdx.x * 256 + t) >> 6;
    if (node >= NN) return;
    int lane = t & 63;
    int fg = lane & 15, es = lane >> 4;
    int start = offsets[node], end = offsets[node + 1];
    float4 acc = make_float4(0.f, 0.f, 0.f, 0.f);
    int k = start + es;
    for (; k + 4 < end; k += 8) {            // 2 edges in flight per lane
        int s0 = csr[k], s1 = csr[k + 4];
        ushort4 u0 = *(const ushort4*)&Hs[s0 * DH + fg * 4];
        ushort4 u1 = *(const ushort4*)&Hs[s1 * DH + fg * 4];
        acc.x += bf2f(u0.x) + bf2f(u1.x);
        acc.y += bf2f(u0.y) + bf2f(u1.y);
        acc.z += bf2f(u0.z) + bf2f(u1.z);
        acc.w += bf2f(u0.w) + bf2f(u1.w);
    }
    if (k < end) {
        int s = csr[k];
        ushort4 u = *(const ushort4*)&Hs[s * DH + fg * 4];
        acc.x += bf2f(u.x); acc.y += bf2f(u.y);
        acc.z += bf2f(u.z); acc.w += bf2f(u.w);
    }
    acc.x += __shfl_xor(acc.x, 16); acc.y += __shfl_xor(acc.y, 16);
    acc.z += __shfl_xor(acc.z, 16); acc.w += __shfl_xor(acc.w, 16);
    acc.x += __shfl_xor(acc.x, 32); acc.y += __shfl_xor(acc.y, 32);
    acc.z += __shfl_xor(acc.z, 32); acc.w += __shfl_xor(acc.w, 32);
    float dv = dinv[node];
    ushort4 su = *(const ushort4*)&Hs[node * DH + fg * 4];
    float4 b4 = *(const float4*)&b1[fg * 4];
    float4 v;
    v.x = fmaxf(dv * (acc.x + bf2f(su.x)) + b4.x, 0.f);
    v.y = fmaxf(dv * (acc.y + bf2f(su.y)) + b4.y, 0.f);
    v.z = fmaxf(dv * (acc.z + bf2f(su.z)) + b4.z, 0.f);
    v.w = fmaxf(dv * (acc.w + bf2f(su.w)) + b4.w, 0.f);
    // fused GEMM2: slot es computes cols es*8..es*8+7
    int col0 = es * 8;
    ush r8[8];
#pragma unroll
    for (int cc = 0; cc < 8; cc++) {
        float4 w = *(const float4*)&W2T[(col0 + cc) * DH + fg * 4];
        float p = v.x * w.x + v.y * w.y + v.z * w.z + v.w * w.w;
        p += __shfl_xor(p, 1); p += __shfl_xor(p, 2);
        p += __shfl_xor(p, 4); p += __shfl_xor(p, 8);
        r8[cc] = f2bf(p * dv);
    }
    if (fg == 0) {
        uint4 pk;
        pk.x = (unsigned)r8[0] | ((unsigned)r8[1] << 16);
        pk.y = (unsigned)r8[2] | ((unsigned)r8[3] << 16);
        pk.z = (unsigned)r8[4] | ((unsigned)r8[5] << 16);
        pk.w = (unsigned)r8[6] | ((unsigned)r8[7] << 16);
        *(uint4*)&Hs2[node * DOUT + col0] = pk;
    }
}

// ---------------- gather2 (F=32 bf16): wave/node, 8 edge-slots x 8 fgroups + fc -------
__global__ __launch_bounds__(256) void gather2_kernel(const int* __restrict__ offsets,
                                                      const int* __restrict__ csr,
                                                      const float* __restrict__ dinv,
                                                      const ush* __restrict__ Hs,
                                                      const float* __restrict__ b2,
                                                      const float* __restrict__ fcw,
                                                      const float* __restrict__ fcb,
                                                      float* __restrict__ h2,
                                                      float* __restrict__ scores) {
    int node = (blockIdx.x * 256 + threadIdx.x) >> 6;
    int lane = threadIdx.x & 63;
    if (node >= NN) return;
    int fg = lane & 7, es = lane >> 3;
    int start = offsets[node], end = offsets[node + 1];
    float4 acc = make_float4(0.f, 0.f, 0.f, 0.f);
    int k = start + es;
    for (; k + 8 < end; k += 16) {           // 2 edges in flight per lane
        int s0 = csr[k], s1 = csr[k + 8];
        ushort4 u0 = *(const ushort4*)&Hs[s0 * DOUT + fg * 4];
        ushort4 u1 = *(const ushort4*)&Hs[s1 * DOUT + fg * 4];
        acc.x += bf2f(u0.x) + bf2f(u1.x);
        acc.y += bf2f(u0.y) + bf2f(u1.y);
        acc.z += bf2f(u0.z) + bf2f(u1.z);
        acc.w += bf2f(u0.w) + bf2f(u1.w);
    }
    if (k < end) {
        int s = csr[k];
        ushort4 u = *(const ushort4*)&Hs[s * DOUT + fg * 4];
        acc.x += bf2f(u.x); acc.y += bf2f(u.y);
        acc.z += bf2f(u.z); acc.w += bf2f(u.w);
    }
#pragma unroll
    for (int m = 8; m <= 32; m <<= 1) {
        acc.x += __shfl_xor(acc.x, m); acc.y += __shfl_xor(acc.y, m);
        acc.z += __shfl_xor(acc.z, m); acc.w += __shfl_xor(acc.w, m);
    }
    float dv = dinv[node];
    ushort4 su = *(const ushort4*)&Hs[node * DOUT + fg * 4];
    float4 b4 = *(const float4*)&b2[fg * 4];
    float4 v;
    v.x = fmaxf(dv * (acc.x + bf2f(su.x)) + b4.x, 0.f);
    v.y = fmaxf(dv * (acc.y + bf2f(su.y)) + b4.y, 0.f);
    v.z = fmaxf(dv * (acc.z + bf2f(su.z)) + b4.z, 0.f);
    v.w = fmaxf(dv * (acc.w + bf2f(su.w)) + b4.w, 0.f);
    if (es == 0) *(float4*)&h2[node * DOUT + fg * 4] = v;
    float4 fw = *(const float4*)&fcw[fg * 4];
    float sv = v.x * fw.x + v.y * fw.y + v.z * fw.z + v.w * fw.w;
    sv += __shfl_xor(sv, 1); sv += __shfl_xor(sv, 2); sv += __shfl_xor(sv, 4);
    if (lane == 0) scores[node] = sv + fcb[0];
}

extern "C" void kernel_launch(void* const* d_in, const int* in_sizes, int n_in,
                              void* d_out, int out_size, void* d_ws, size_t ws_size,
                              hipStream_t stream) {
    const float* x   = (const float*)d_in[0];
    const int*   ei  = (const int*)d_in[1];
    const float* W1  = (const float*)d_in[2];
    const float* b1  = (const float*)d_in[3];
    const float* W2  = (const float*)d_in[4];
    const float* b2  = (const float*)d_in[5];
    const float* fcw = (const float*)d_in[6];
    const float* fcb = (const float*)d_in[7];
    const int* src = ei;
    const int* dst = ei + EE;

    float* ws = (float*)d_ws;
    float* dinv    = ws;                          // NN f
    int*   offsets = (int*)(ws + NN);             // NN+1 i
    int*   bcnt    = (int*)(ws + 2 * NN + 64);    // NBUCK
    int*   bbase   = bcnt + 512;
    int*   bcur    = bbase + 512;
    int*   csr     = bcur + 512;                  // EE i
    unsigned* tmp  = (unsigned*)(csr + EE);       // EE u32
    ush*   Hs1     = (ush*)(ws + 3401600);        // NN*64 bf16 (16B-aligned)
    ush*   Hs2     = (ush*)(ws + 6601600);        // NN*32 bf16 (16B-aligned)

    float* out    = (float*)d_out;
    float* scores = out;          // NN
    float* h2     = out + NN;     // NN*32

    const int T = 256;
    // CSR build (two-pass binning)
    zero_bcnt_kernel<<<2, 256, 0, stream>>>(bcnt);
    bhist_kernel<<<NCHUNK, T, 0, stream>>>(dst, bcnt);
    bscan_kernel<<<1, T, 0, stream>>>(bcnt, bbase, bcur, offsets);
    binA_kernel<<<NCHUNK, T, 0, stream>>>(src, dst, bcur, tmp);
    binB_kernel<<<NBUCK, T, 0, stream>>>(tmp, bbase, csr, offsets, dinv);
    // layer 1: Hs1 = bf16((x@W1)*dinv)
    gemm_bf_kernel<DIN, DH><<<(NN + 63) / 64, T, 0, stream>>>(x, W1, dinv, Hs1);
    // gather1 + fused GEMM2 -> Hs2 = bf16((relu-agg @ W2)*dinv)
    gather1_kernel<<<(NN * 64 + T - 1) / T, T, 0, stream>>>(offsets, csr, dinv, Hs1, b1, W2, Hs2);
    // layer 2 aggregate + fc
    gather2_kernel<<<(NN * 64 + T - 1) / T, T, 0, stream>>>(offsets, csr, dinv, Hs2, b2, fcw, fcb, h2, scores);
}

// Round 7
// 292.116 us; speedup vs baseline: 1.2195x; 1.2195x over previous
//
#include <hip/hip_runtime.h>

#define NN 100000
#define EE 1600000
#define DIN 128
#define DH 64
#define DOUT 32

#define BSH 8                      // bucket = dst >> 8  (256 nodes/bucket)
#define BNODES 256
#define NBUCK ((NN + BNODES - 1) / BNODES)   // 391
#define CHUNK 4096                 // edges per Pass-A workgroup
#define NCHUNK ((EE + CHUNK - 1) / CHUNK)    // 391

typedef unsigned short ush;

__device__ __forceinline__ float bf2f(ush u) {
    union { unsigned u; float f; } c; c.u = ((unsigned)u) << 16; return c.f;
}
__device__ __forceinline__ ush f2bf(float f) {
    union { float f; unsigned u; } c; c.f = f;
    unsigned r = c.u + 0x7fff + ((c.u >> 16) & 1);   // round-to-nearest-even
    return (ush)(r >> 16);
}

// ---------------- zero bucket counters ----------------
__global__ void zero_bcnt_kernel(int* __restrict__ bcnt) {
    int i = blockIdx.x * 256 + threadIdx.x;
    if (i < NBUCK) bcnt[i] = 0;
}

// ---------------- bucket histogram (LDS-first) ----------------
__global__ __launch_bounds__(256) void bhist_kernel(const int* __restrict__ dst,
                                                    int* __restrict__ bcnt) {
    __shared__ int h[NBUCK];
    int t = threadIdx.x;
    for (int i = t; i < NBUCK; i += 256) h[i] = 0;
    __syncthreads();
    int base = blockIdx.x * CHUNK;
    int end = min(base + CHUNK, EE);
    for (int i = base + t; i < end; i += 256) atomicAdd(&h[dst[i] >> BSH], 1);
    __syncthreads();
    for (int i = t; i < NBUCK; i += 256) if (h[i]) atomicAdd(&bcnt[i], h[i]);
}

// ---------------- bucket exclusive scan (1 wg) ----------------
__global__ __launch_bounds__(256) void bscan_kernel(const int* __restrict__ bcnt,
                                                    int* __restrict__ bbase,
                                                    int* __restrict__ bcur,
                                                    int* __restrict__ offsets) {
    __shared__ int s2[256];
    int t = threadIdx.x;
    int a0 = (2 * t < NBUCK) ? bcnt[2 * t] : 0;
    int a1 = (2 * t + 1 < NBUCK) ? bcnt[2 * t + 1] : 0;
    s2[t] = a0 + a1;
    __syncthreads();
    for (int off = 1; off < 256; off <<= 1) {
        int x = (t >= off) ? s2[t - off] : 0;
        __syncthreads();
        s2[t] += x;
        __syncthreads();
    }
    int excl = s2[t] - a0 - a1;
    if (2 * t < NBUCK)     { bbase[2 * t] = excl;          bcur[2 * t] = excl; }
    if (2 * t + 1 < NBUCK) { bbase[2 * t + 1] = excl + a0; bcur[2 * t + 1] = excl + a0; }
    if (t == 255) { bbase[NBUCK] = s2[255]; offsets[NN] = s2[255]; }  // = EE
}

// ---------------- Pass A: bin edges into bucket-grouped tmp (packed (src<<8)|dstlow) ----
__global__ __launch_bounds__(256) void binA_kernel(const int* __restrict__ src,
                                                   const int* __restrict__ dst,
                                                   int* __restrict__ bcur,
                                                   unsigned* __restrict__ tmp) {
    __shared__ int hist[NBUCK];
    __shared__ int scn[NBUCK + 1];
    __shared__ int cur[NBUCK];
    __shared__ int gbase[NBUCK];
    __shared__ int s2[256];
    __shared__ unsigned staged[CHUNK];
    int t = threadIdx.x;
    for (int i = t; i < NBUCK; i += 256) hist[i] = 0;
    __syncthreads();
    int e0 = blockIdx.x * CHUNK;
    int nE = min(CHUNK, EE - e0);

    int my_e[16], my_bk[16];
#pragma unroll
    for (int k = 0; k < 16; k++) {
        int li = t + k * 256;
        bool ok = li < nE;
        int idx = ok ? (e0 + li) : e0;
        int d = dst[idx];
        int s = src[idx];
        int b = d >> BSH;
        my_e[k] = (s << 8) | (d & 255);
        my_bk[k] = ok ? b : -1;
        if (ok) atomicAdd(&hist[b], 1);
    }
    __syncthreads();
    int a0 = (2 * t < NBUCK) ? hist[2 * t] : 0;
    int a1 = (2 * t + 1 < NBUCK) ? hist[2 * t + 1] : 0;
    s2[t] = a0 + a1;
    __syncthreads();
    for (int off = 1; off < 256; off <<= 1) {
        int x = (t >= off) ? s2[t - off] : 0;
        __syncthreads();
        s2[t] += x;
        __syncthreads();
    }
    int excl = s2[t] - a0 - a1;
    if (2 * t < NBUCK)     { scn[2 * t] = excl;          cur[2 * t] = excl; }
    if (2 * t + 1 < NBUCK) { scn[2 * t + 1] = excl + a0; cur[2 * t + 1] = excl + a0; }
    if (t == 0) scn[NBUCK] = nE;
    __syncthreads();
    for (int i = t; i < NBUCK; i += 256)
        gbase[i] = hist[i] ? atomicAdd(&bcur[i], hist[i]) : 0;
    __syncthreads();
#pragma unroll
    for (int k = 0; k < 16; k++) {
        if (my_bk[k] >= 0) {
            int lp = atomicAdd(&cur[my_bk[k]], 1);
            staged[lp] = (unsigned)my_e[k];
        }
    }
    __syncthreads();
    for (int i = t; i < nE; i += 256) {
        int lo = 0, hi = NBUCK;
#pragma unroll
        for (int step = 0; step < 9; step++) {
            int mid = (lo + hi) >> 1;
            bool c = scn[mid] <= i;
            lo = c ? mid : lo;
            hi = c ? hi : mid;
        }
        tmp[gbase[lo] + (i - scn[lo])] = staged[i];
    }
}

// ---------------- Pass B: per-bucket node histogram + scan -> offsets/dinv/csr ----------
__global__ __launch_bounds__(256) void binB_kernel(const unsigned* __restrict__ tmp,
                                                   const int* __restrict__ bbase,
                                                   int* __restrict__ csr,
                                                   int* __restrict__ offsets,
                                                   float* __restrict__ dinv) {
    __shared__ int hist[BNODES], cur[BNODES], sc[BNODES];
    int b = blockIdx.x, t = threadIdx.x;
    int e0 = bbase[b], e1 = bbase[b + 1];
    hist[t] = 0;
    __syncthreads();
    for (int i = e0 + t; i < e1; i += 256) atomicAdd(&hist[tmp[i] & 255], 1);
    __syncthreads();
    int v = hist[t];
    sc[t] = v;
    __syncthreads();
    for (int off = 1; off < 256; off <<= 1) {
        int x = (t >= off) ? sc[t - off] : 0;
        __syncthreads();
        sc[t] += x;
        __syncthreads();
    }
    int excl = sc[t] - v;
    cur[t] = e0 + excl;
    int node = (b << BSH) + t;
    if (node < NN) {
        offsets[node] = e0 + excl;
        dinv[node] = 1.0f / sqrtf((float)v + 1.0f);
    }
    __syncthreads();
    for (int i = e0 + t; i < e1; i += 256) {
        unsigned u = tmp[i];
        int pos = atomicAdd(&cur[u & 255], 1);
        csr[pos] = (int)(u >> 8);
    }
}

// ---------------- GEMM + dinv-scale, bf16 out: Y[r,:] = bf16((X[r,:]@W) * dinv[r]) -----
// 256 threads; each thread computes 4 rows x 4 cols. X tile padded in LDS.
template <int K, int NC>
__global__ __launch_bounds__(256) void gemm_bf_kernel(const float* __restrict__ X,
                                                      const float* __restrict__ W,
                                                      const float* __restrict__ dinv,
                                                      ush* __restrict__ Y) {
    constexpr int CG   = NC / 4;
    constexpr int RS   = 256 / CG;
    constexpr int ROWS = RS * 4;
    constexpr int XP   = K + 4;
    __shared__ float Wl[K * NC];
    __shared__ float Xl[ROWS * XP];
    const int t = threadIdx.x;
    const int row0 = blockIdx.x * ROWS;

    for (int i = t; i < K * (NC / 4); i += 256) {
        int k = i / (NC / 4), c = i % (NC / 4);
        *(float4*)&Wl[k * NC + c * 4] = *(const float4*)&W[k * NC + c * 4];
    }
    for (int i = t; i < ROWS * (K / 4); i += 256) {
        int r = i / (K / 4), c = i % (K / 4);
        float4 v = make_float4(0.f, 0.f, 0.f, 0.f);
        if (row0 + r < NN) v = *(const float4*)&X[(row0 + r) * K + c * 4];
        *(float4*)&Xl[r * XP + c * 4] = v;
    }
    __syncthreads();

    const int cg = t & (CG - 1);
    const int rs = t / CG;
    float4 acc[4];
#pragma unroll
    for (int rr = 0; rr < 4; rr++) acc[rr] = make_float4(0.f, 0.f, 0.f, 0.f);

#pragma unroll 4
    for (int k = 0; k < K; k += 4) {
        float4 w0 = *(const float4*)&Wl[(k + 0) * NC + cg * 4];
        float4 w1 = *(const float4*)&Wl[(k + 1) * NC + cg * 4];
        float4 w2 = *(const float4*)&Wl[(k + 2) * NC + cg * 4];
        float4 w3 = *(const float4*)&Wl[(k + 3) * NC + cg * 4];
#pragma unroll
        for (int rr = 0; rr < 4; rr++) {
            float4 xv = *(const float4*)&Xl[(rs * 4 + rr) * XP + k];
            acc[rr].x += xv.x * w0.x + xv.y * w1.x + xv.z * w2.x + xv.w * w3.x;
            acc[rr].y += xv.x * w0.y + xv.y * w1.y + xv.z * w2.y + xv.w * w3.y;
            acc[rr].z += xv.x * w0.z + xv.y * w1.z + xv.z * w2.z + xv.w * w3.z;
            acc[rr].w += xv.x * w0.w + xv.y * w1.w + xv.z * w2.w + xv.w * w3.w;
        }
    }
#pragma unroll
    for (int rr = 0; rr < 4; rr++) {
        int row = row0 + rs * 4 + rr;
        if (row < NN) {
            float s = dinv[row];
            ushort4 o;
            o.x = f2bf(acc[rr].x * s); o.y = f2bf(acc[rr].y * s);
            o.z = f2bf(acc[rr].z * s); o.w = f2bf(acc[rr].w * s);
            *(ushort4*)&Y[row * NC + cg * 4] = o;
        }
    }
}

// ---------------- gather1 (F=64 bf16): wave/node, 4 edge-slots x 16 fgroups, unroll 4 --
// h1 = relu(dv*(sum Hs1[s] + Hs1[node]) + b1), written fp32
__global__ __launch_bounds__(256) void gather1_kernel(const int* __restrict__ offsets,
                                                      const int* __restrict__ csr,
                                                      const float* __restrict__ dinv,
                                                      const ush* __restrict__ Hs,
                                                      const float* __restrict__ b1,
                                                      float* __restrict__ h1) {
    int node = (blockIdx.x * 256 + threadIdx.x) >> 6;
    int lane = threadIdx.x & 63;
    if (node >= NN) return;
    int fg = lane & 15, es = lane >> 4;
    int start = offsets[node], end = offsets[node + 1];
    float4 acc = make_float4(0.f, 0.f, 0.f, 0.f);
    int k = start + es;
    for (; k + 12 < end; k += 16) {          // 4 independent rows in flight per slot
        int s0 = csr[k], s1 = csr[k + 4], s2 = csr[k + 8], s3 = csr[k + 12];
        ushort4 u0 = *(const ushort4*)&Hs[s0 * DH + fg * 4];
        ushort4 u1 = *(const ushort4*)&Hs[s1 * DH + fg * 4];
        ushort4 u2 = *(const ushort4*)&Hs[s2 * DH + fg * 4];
        ushort4 u3 = *(const ushort4*)&Hs[s3 * DH + fg * 4];
        acc.x += (bf2f(u0.x) + bf2f(u1.x)) + (bf2f(u2.x) + bf2f(u3.x));
        acc.y += (bf2f(u0.y) + bf2f(u1.y)) + (bf2f(u2.y) + bf2f(u3.y));
        acc.z += (bf2f(u0.z) + bf2f(u1.z)) + (bf2f(u2.z) + bf2f(u3.z));
        acc.w += (bf2f(u0.w) + bf2f(u1.w)) + (bf2f(u2.w) + bf2f(u3.w));
    }
    for (; k < end; k += 4) {
        int s = csr[k];
        ushort4 u = *(const ushort4*)&Hs[s * DH + fg * 4];
        acc.x += bf2f(u.x); acc.y += bf2f(u.y);
        acc.z += bf2f(u.z); acc.w += bf2f(u.w);
    }
    acc.x += __shfl_xor(acc.x, 16); acc.y += __shfl_xor(acc.y, 16);
    acc.z += __shfl_xor(acc.z, 16); acc.w += __shfl_xor(acc.w, 16);
    acc.x += __shfl_xor(acc.x, 32); acc.y += __shfl_xor(acc.y, 32);
    acc.z += __shfl_xor(acc.z, 32); acc.w += __shfl_xor(acc.w, 32);
    float dv = dinv[node];
    ushort4 su = *(const ushort4*)&Hs[node * DH + fg * 4];
    float4 b4 = *(const float4*)&b1[fg * 4];
    float4 v;
    v.x = fmaxf(dv * (acc.x + bf2f(su.x)) + b4.x, 0.f);
    v.y = fmaxf(dv * (acc.y + bf2f(su.y)) + b4.y, 0.f);
    v.z = fmaxf(dv * (acc.z + bf2f(su.z)) + b4.z, 0.f);
    v.w = fmaxf(dv * (acc.w + bf2f(su.w)) + b4.w, 0.f);
    if (es == 0) *(float4*)&h1[node * DH + fg * 4] = v;
}

// ---------------- gather2 (F=32 bf16): wave/node, 8 edge-slots x 8 fgroups + fc -------
__global__ __launch_bounds__(256) void gather2_kernel(const int* __restrict__ offsets,
                                                      const int* __restrict__ csr,
                                                      const float* __restrict__ dinv,
                                                      const ush* __restrict__ Hs,
                                                      const float* __restrict__ b2,
                                                      const float* __restrict__ fcw,
                                                      const float* __restrict__ fcb,
                                                      float* __restrict__ h2,
                                                      float* __restrict__ scores) {
    int node = (blockIdx.x * 256 + threadIdx.x) >> 6;
    int lane = threadIdx.x & 63;
    if (node >= NN) return;
    int fg = lane & 7, es = lane >> 3;
    int start = offsets[node], end = offsets[node + 1];
    float4 acc = make_float4(0.f, 0.f, 0.f, 0.f);
    int k = start + es;
    for (; k + 8 < end; k += 16) {           // 2 rows in flight per slot
        int s0 = csr[k], s1 = csr[k + 8];
        ushort4 u0 = *(const ushort4*)&Hs[s0 * DOUT + fg * 4];
        ushort4 u1 = *(const ushort4*)&Hs[s1 * DOUT + fg * 4];
        acc.x += bf2f(u0.x) + bf2f(u1.x);
        acc.y += bf2f(u0.y) + bf2f(u1.y);
        acc.z += bf2f(u0.z) + bf2f(u1.z);
        acc.w += bf2f(u0.w) + bf2f(u1.w);
    }
    if (k < end) {
        int s = csr[k];
        ushort4 u = *(const ushort4*)&Hs[s * DOUT + fg * 4];
        acc.x += bf2f(u.x); acc.y += bf2f(u.y);
        acc.z += bf2f(u.z); acc.w += bf2f(u.w);
    }
#pragma unroll
    for (int m = 8; m <= 32; m <<= 1) {
        acc.x += __shfl_xor(acc.x, m); acc.y += __shfl_xor(acc.y, m);
        acc.z += __shfl_xor(acc.z, m); acc.w += __shfl_xor(acc.w, m);
    }
    float dv = dinv[node];
    ushort4 su = *(const ushort4*)&Hs[node * DOUT + fg * 4];
    float4 b4 = *(const float4*)&b2[fg * 4];
    float4 v;
    v.x = fmaxf(dv * (acc.x + bf2f(su.x)) + b4.x, 0.f);
    v.y = fmaxf(dv * (acc.y + bf2f(su.y)) + b4.y, 0.f);
    v.z = fmaxf(dv * (acc.z + bf2f(su.z)) + b4.z, 0.f);
    v.w = fmaxf(dv * (acc.w + bf2f(su.w)) + b4.w, 0.f);
    if (es == 0) *(float4*)&h2[node * DOUT + fg * 4] = v;
    float4 fw = *(const float4*)&fcw[fg * 4];
    float sv = v.x * fw.x + v.y * fw.y + v.z * fw.z + v.w * fw.w;
    sv += __shfl_xor(sv, 1); sv += __shfl_xor(sv, 2); sv += __shfl_xor(sv, 4);
    if (lane == 0) scores[node] = sv + fcb[0];
}

extern "C" void kernel_launch(void* const* d_in, const int* in_sizes, int n_in,
                              void* d_out, int out_size, void* d_ws, size_t ws_size,
                              hipStream_t stream) {
    const float* x   = (const float*)d_in[0];
    const int*   ei  = (const int*)d_in[1];
    const float* W1  = (const float*)d_in[2];
    const float* b1  = (const float*)d_in[3];
    const float* W2  = (const float*)d_in[4];
    const float* b2  = (const float*)d_in[5];
    const float* fcw = (const float*)d_in[6];
    const float* fcb = (const float*)d_in[7];
    const int* src = ei;
    const int* dst = ei + EE;

    float* ws = (float*)d_ws;
    float* dinv    = ws;                          // NN f
    int*   offsets = (int*)(ws + NN);             // NN+1 i
    int*   bcnt    = (int*)(ws + 2 * NN + 64);    // NBUCK
    int*   bbase   = bcnt + 512;
    int*   bcur    = bbase + 512;
    int*   csr     = bcur + 512;                  // EE i, ends @ f-off 1,801,600
    unsigned* tmp  = (unsigned*)(csr + EE);       // EE u32, ends @ 3,401,600
    ush*   Hs1     = (ush*)(ws + 3401600);        // NN*64 bf16 (3.2M f), ends @ 6,601,600
    ush*   Hs2     = (ush*)(ws + 6601600);        // NN*32 bf16 (1.6M f), ends @ 8,201,600
    float* h1      = ws + 8201600;                // NN*64 fp32, ends @ 14,601,600 (58.4 MB; r5 used 71 MB OK)

    float* out    = (float*)d_out;
    float* scores = out;          // NN
    float* h2     = out + NN;     // NN*32

    const int T = 256;
    // CSR build (two-pass binning)
    zero_bcnt_kernel<<<2, 256, 0, stream>>>(bcnt);
    bhist_kernel<<<NCHUNK, T, 0, stream>>>(dst, bcnt);
    bscan_kernel<<<1, T, 0, stream>>>(bcnt, bbase, bcur, offsets);
    binA_kernel<<<NCHUNK, T, 0, stream>>>(src, dst, bcur, tmp);
    binB_kernel<<<NBUCK, T, 0, stream>>>(tmp, bbase, csr, offsets, dinv);
    // layer 1: Hs1 = bf16((x@W1)*dinv)
    gemm_bf_kernel<DIN, DH><<<(NN + 63) / 64, T, 0, stream>>>(x, W1, dinv, Hs1);
    gather1_kernel<<<(NN * 64 + T - 1) / T, T, 0, stream>>>(offsets, csr, dinv, Hs1, b1, h1);
    // layer 2: Hs2 = bf16((h1@W2)*dinv)
    gemm_bf_kernel<DH, DOUT><<<(NN + 127) / 128, T, 0, stream>>>(h1, W2, dinv, Hs2);
    gather2_kernel<<<(NN * 64 + T - 1) / T, T, 0, stream>>>(offsets, csr, dinv, Hs2, b2, fcw, fcb, h2, scores);
}

// Round 8
// 282.334 us; speedup vs baseline: 1.2618x; 1.0346x over previous
//
#include <hip/hip_runtime.h>

#define NN 100000
#define EE 1600000
#define DIN 128
#define DH 64
#define DOUT 32

#define BSH 8                      // bucket = dst >> 8  (256 nodes/bucket)
#define BNODES 256
#define NBUCK ((NN + BNODES - 1) / BNODES)   // 391
#define CHUNK 4096                 // edges per Pass-A workgroup
#define NCHUNK ((EE + CHUNK - 1) / CHUNK)    // 391

typedef unsigned short ush;

__device__ __forceinline__ float bflo(unsigned u) {
    union { unsigned u; float f; } c; c.u = u << 16; return c.f;
}
__device__ __forceinline__ float bfhi(unsigned u) {
    union { unsigned u; float f; } c; c.u = u & 0xffff0000u; return c.f;
}
__device__ __forceinline__ ush f2bf(float f) {
    union { float f; unsigned u; } c; c.f = f;
    unsigned r = c.u + 0x7fff + ((c.u >> 16) & 1);   // round-to-nearest-even
    return (ush)(r >> 16);
}

// ---------------- zero bucket counters ----------------
__global__ void zero_bcnt_kernel(int* __restrict__ bcnt) {
    int i = blockIdx.x * 256 + threadIdx.x;
    if (i < NBUCK) bcnt[i] = 0;
}

// ---------------- bucket histogram (LDS-first) ----------------
__global__ __launch_bounds__(256) void bhist_kernel(const int* __restrict__ dst,
                                                    int* __restrict__ bcnt) {
    __shared__ int h[NBUCK];
    int t = threadIdx.x;
    for (int i = t; i < NBUCK; i += 256) h[i] = 0;
    __syncthreads();
    int base = blockIdx.x * CHUNK;
    int end = min(base + CHUNK, EE);
    for (int i = base + t; i < end; i += 256) atomicAdd(&h[dst[i] >> BSH], 1);
    __syncthreads();
    for (int i = t; i < NBUCK; i += 256) if (h[i]) atomicAdd(&bcnt[i], h[i]);
}

// ---------------- bucket exclusive scan (1 wg) ----------------
__global__ __launch_bounds__(256) void bscan_kernel(const int* __restrict__ bcnt,
                                                    int* __restrict__ bbase,
                                                    int* __restrict__ bcur,
                                                    int* __restrict__ offsets) {
    __shared__ int s2[256];
    int t = threadIdx.x;
    int a0 = (2 * t < NBUCK) ? bcnt[2 * t] : 0;
    int a1 = (2 * t + 1 < NBUCK) ? bcnt[2 * t + 1] : 0;
    s2[t] = a0 + a1;
    __syncthreads();
    for (int off = 1; off < 256; off <<= 1) {
        int x = (t >= off) ? s2[t - off] : 0;
        __syncthreads();
        s2[t] += x;
        __syncthreads();
    }
    int excl = s2[t] - a0 - a1;
    if (2 * t < NBUCK)     { bbase[2 * t] = excl;          bcur[2 * t] = excl; }
    if (2 * t + 1 < NBUCK) { bbase[2 * t + 1] = excl + a0; bcur[2 * t + 1] = excl + a0; }
    if (t == 255) { bbase[NBUCK] = s2[255]; offsets[NN] = s2[255]; }  // = EE
}

// ---------------- Pass A: bin edges into bucket-grouped tmp (packed (src<<8)|dstlow) ----
__global__ __launch_bounds__(256) void binA_kernel(const int* __restrict__ src,
                                                   const int* __restrict__ dst,
                                                   int* __restrict__ bcur,
                                                   unsigned* __restrict__ tmp) {
    __shared__ int hist[NBUCK];
    __shared__ int scn[NBUCK + 1];
    __shared__ int cur[NBUCK];
    __shared__ int gbase[NBUCK];
    __shared__ int s2[256];
    __shared__ unsigned staged[CHUNK];
    int t = threadIdx.x;
    for (int i = t; i < NBUCK; i += 256) hist[i] = 0;
    __syncthreads();
    int e0 = blockIdx.x * CHUNK;
    int nE = min(CHUNK, EE - e0);

    int my_e[16], my_bk[16];
#pragma unroll
    for (int k = 0; k < 16; k++) {
        int li = t + k * 256;
        bool ok = li < nE;
        int idx = ok ? (e0 + li) : e0;
        int d = dst[idx];
        int s = src[idx];
        int b = d >> BSH;
        my_e[k] = (s << 8) | (d & 255);
        my_bk[k] = ok ? b : -1;
        if (ok) atomicAdd(&hist[b], 1);
    }
    __syncthreads();
    int a0 = (2 * t < NBUCK) ? hist[2 * t] : 0;
    int a1 = (2 * t + 1 < NBUCK) ? hist[2 * t + 1] : 0;
    s2[t] = a0 + a1;
    __syncthreads();
    for (int off = 1; off < 256; off <<= 1) {
        int x = (t >= off) ? s2[t - off] : 0;
        __syncthreads();
        s2[t] += x;
        __syncthreads();
    }
    int excl = s2[t] - a0 - a1;
    if (2 * t < NBUCK)     { scn[2 * t] = excl;          cur[2 * t] = excl; }
    if (2 * t + 1 < NBUCK) { scn[2 * t + 1] = excl + a0; cur[2 * t + 1] = excl + a0; }
    if (t == 0) scn[NBUCK] = nE;
    __syncthreads();
    for (int i = t; i < NBUCK; i += 256)
        gbase[i] = hist[i] ? atomicAdd(&bcur[i], hist[i]) : 0;
    __syncthreads();
#pragma unroll
    for (int k = 0; k < 16; k++) {
        if (my_bk[k] >= 0) {
            int lp = atomicAdd(&cur[my_bk[k]], 1);
            staged[lp] = (unsigned)my_e[k];
        }
    }
    __syncthreads();
    for (int i = t; i < nE; i += 256) {
        int lo = 0, hi = NBUCK;
#pragma unroll
        for (int step = 0; step < 9; step++) {
            int mid = (lo + hi) >> 1;
            bool c = scn[mid] <= i;
            lo = c ? mid : lo;
            hi = c ? hi : mid;
        }
        tmp[gbase[lo] + (i - scn[lo])] = staged[i];
    }
}

// ---------------- Pass B: per-bucket node histogram + scan -> offsets/dinv/csr ----------
__global__ __launch_bounds__(256) void binB_kernel(const unsigned* __restrict__ tmp,
                                                   const int* __restrict__ bbase,
                                                   int* __restrict__ csr,
                                                   int* __restrict__ offsets,
                                                   float* __restrict__ dinv) {
    __shared__ int hist[BNODES], cur[BNODES], sc[BNODES];
    int b = blockIdx.x, t = threadIdx.x;
    int e0 = bbase[b], e1 = bbase[b + 1];
    hist[t] = 0;
    __syncthreads();
    for (int i = e0 + t; i < e1; i += 256) atomicAdd(&hist[tmp[i] & 255], 1);
    __syncthreads();
    int v = hist[t];
    sc[t] = v;
    __syncthreads();
    for (int off = 1; off < 256; off <<= 1) {
        int x = (t >= off) ? sc[t - off] : 0;
        __syncthreads();
        sc[t] += x;
        __syncthreads();
    }
    int excl = sc[t] - v;
    cur[t] = e0 + excl;
    int node = (b << BSH) + t;
    if (node < NN) {
        offsets[node] = e0 + excl;
        dinv[node] = 1.0f / sqrtf((float)v + 1.0f);
    }
    __syncthreads();
    for (int i = e0 + t; i < e1; i += 256) {
        unsigned u = tmp[i];
        int pos = atomicAdd(&cur[u & 255], 1);
        csr[pos] = (int)(u >> 8);
    }
}

// ---------------- GEMM + dinv-scale, bf16 out: Y[r,:] = bf16((X[r,:]@W) * dinv[r]) -----
// W staged in LDS (32/8 KB only); X streamed from global (L1-broadcast across cg lanes).
// Each thread: 4 rows x 4 cols.
template <int K, int NC>
__global__ __launch_bounds__(256) void gemm_bf_kernel(const float* __restrict__ X,
                                                      const float* __restrict__ W,
                                                      const float* __restrict__ dinv,
                                                      ush* __restrict__ Y) {
    constexpr int CG   = NC / 4;
    constexpr int RS   = 256 / CG;
    constexpr int ROWS = RS * 4;
    __shared__ float Wl[K * NC];
    const int t = threadIdx.x;
    const int row0 = blockIdx.x * ROWS;

    for (int i = t; i < K * (NC / 4); i += 256)
        *(float4*)&Wl[i * 4] = *(const float4*)&W[i * 4];
    __syncthreads();

    const int cg = t & (CG - 1);
    const int rs = t / CG;
    const int r0 = row0 + rs * 4;
    // clamp row pointers for safe reads; stores are guarded
    const float* xp0 = X + (size_t)((r0 + 0) < NN ? (r0 + 0) : (NN - 1)) * K;
    const float* xp1 = X + (size_t)((r0 + 1) < NN ? (r0 + 1) : (NN - 1)) * K;
    const float* xp2 = X + (size_t)((r0 + 2) < NN ? (r0 + 2) : (NN - 1)) * K;
    const float* xp3 = X + (size_t)((r0 + 3) < NN ? (r0 + 3) : (NN - 1)) * K;

    float4 a0 = make_float4(0.f, 0.f, 0.f, 0.f), a1 = a0, a2 = a0, a3 = a0;

#define ROWFMA(acc, xv)                                              \
    acc.x += xv.x * w0.x + xv.y * w1.x + xv.z * w2.x + xv.w * w3.x;  \
    acc.y += xv.x * w0.y + xv.y * w1.y + xv.z * w2.y + xv.w * w3.y;  \
    acc.z += xv.x * w0.z + xv.y * w1.z + xv.z * w2.z + xv.w * w3.z;  \
    acc.w += xv.x * w0.w + xv.y * w1.w + xv.z * w2.w + xv.w * w3.w;

#pragma unroll 2
    for (int k = 0; k < K; k += 4) {
        float4 x0 = *(const float4*)&xp0[k];
        float4 x1 = *(const float4*)&xp1[k];
        float4 x2 = *(const float4*)&xp2[k];
        float4 x3 = *(const float4*)&xp3[k];
        float4 w0 = *(const float4*)&Wl[(k + 0) * NC + cg * 4];
        float4 w1 = *(const float4*)&Wl[(k + 1) * NC + cg * 4];
        float4 w2 = *(const float4*)&Wl[(k + 2) * NC + cg * 4];
        float4 w3 = *(const float4*)&Wl[(k + 3) * NC + cg * 4];
        ROWFMA(a0, x0) ROWFMA(a1, x1) ROWFMA(a2, x2) ROWFMA(a3, x3)
    }
#undef ROWFMA

    float4 accs[4] = {a0, a1, a2, a3};
#pragma unroll
    for (int rr = 0; rr < 4; rr++) {
        int row = r0 + rr;
        if (row < NN) {
            float s = dinv[row];
            ushort4 o;
            o.x = f2bf(accs[rr].x * s); o.y = f2bf(accs[rr].y * s);
            o.z = f2bf(accs[rr].z * s); o.w = f2bf(accs[rr].w * s);
            *(ushort4*)&Y[row * NC + cg * 4] = o;
        }
    }
}

#define ACC8(u4)                                      \
    acc0 += bflo(u4.x); acc1 += bfhi(u4.x);           \
    acc2 += bflo(u4.y); acc3 += bfhi(u4.y);           \
    acc4 += bflo(u4.z); acc5 += bfhi(u4.z);           \
    acc6 += bflo(u4.w); acc7 += bfhi(u4.w);

// ---------------- gather1 (F=64 bf16): wave/node, 8 edge-slots x 8 fgroups, uint4 loads -
// h1 = relu(dv*(sum Hs1[s] + Hs1[node]) + b1), written fp32
__global__ __launch_bounds__(256) void gather1_kernel(const int* __restrict__ offsets,
                                                      const int* __restrict__ csr,
                                                      const float* __restrict__ dinv,
                                                      const ush* __restrict__ Hs,
                                                      const float* __restrict__ b1,
                                                      float* __restrict__ h1) {
    int node = (blockIdx.x * 256 + threadIdx.x) >> 6;
    int lane = threadIdx.x & 63;
    if (node >= NN) return;
    int fg = lane & 7, es = lane >> 3;     // 8 fgroups x 8 bf16, 8 edge slots
    int start = offsets[node], end = offsets[node + 1];
    float acc0 = 0.f, acc1 = 0.f, acc2 = 0.f, acc3 = 0.f;
    float acc4 = 0.f, acc5 = 0.f, acc6 = 0.f, acc7 = 0.f;
    int k = start + es;
    for (; k + 8 < end; k += 16) {         // 2 rows in flight per lane (16 per wave)
        int s0 = csr[k], s1 = csr[k + 8];
        uint4 u0 = *(const uint4*)&Hs[s0 * DH + fg * 8];
        uint4 u1 = *(const uint4*)&Hs[s1 * DH + fg * 8];
        ACC8(u0) ACC8(u1)
    }
    if (k < end) {
        int s = csr[k];
        uint4 u = *(const uint4*)&Hs[s * DH + fg * 8];
        ACC8(u)
    }
#pragma unroll
    for (int m = 8; m <= 32; m <<= 1) {
        acc0 += __shfl_xor(acc0, m); acc1 += __shfl_xor(acc1, m);
        acc2 += __shfl_xor(acc2, m); acc3 += __shfl_xor(acc3, m);
        acc4 += __shfl_xor(acc4, m); acc5 += __shfl_xor(acc5, m);
        acc6 += __shfl_xor(acc6, m); acc7 += __shfl_xor(acc7, m);
    }
    float dv = dinv[node];
    uint4 su = *(const uint4*)&Hs[node * DH + fg * 8];
    float4 ba = *(const float4*)&b1[fg * 8];
    float4 bb = *(const float4*)&b1[fg * 8 + 4];
    float4 o0, o1;
    o0.x = fmaxf(dv * (acc0 + bflo(su.x)) + ba.x, 0.f);
    o0.y = fmaxf(dv * (acc1 + bfhi(su.x)) + ba.y, 0.f);
    o0.z = fmaxf(dv * (acc2 + bflo(su.y)) + ba.z, 0.f);
    o0.w = fmaxf(dv * (acc3 + bfhi(su.y)) + ba.w, 0.f);
    o1.x = fmaxf(dv * (acc4 + bflo(su.z)) + bb.x, 0.f);
    o1.y = fmaxf(dv * (acc5 + bfhi(su.z)) + bb.y, 0.f);
    o1.z = fmaxf(dv * (acc6 + bflo(su.w)) + bb.z, 0.f);
    o1.w = fmaxf(dv * (acc7 + bfhi(su.w)) + bb.w, 0.f);
    if (es == 0) {
        *(float4*)&h1[node * DH + fg * 8] = o0;
        *(float4*)&h1[node * DH + fg * 8 + 4] = o1;
    }
}

// ---------------- gather2 (F=32 bf16): wave/node, 16 edge-slots x 4 fgroups + fc -------
__global__ __launch_bounds__(256) void gather2_kernel(const int* __restrict__ offsets,
                                                      const int* __restrict__ csr,
                                                      const float* __restrict__ dinv,
                                                      const ush* __restrict__ Hs,
                                                      const float* __restrict__ b2,
                                                      const float* __restrict__ fcw,
                                                      const float* __restrict__ fcb,
                                                      float* __restrict__ h2,
                                                      float* __restrict__ scores) {
    int node = (blockIdx.x * 256 + threadIdx.x) >> 6;
    int lane = threadIdx.x & 63;
    if (node >= NN) return;
    int fg = lane & 3, es = lane >> 2;     // 4 fgroups x 8 bf16, 16 edge slots
    int start = offsets[node], end = offsets[node + 1];
    float acc0 = 0.f, acc1 = 0.f, acc2 = 0.f, acc3 = 0.f;
    float acc4 = 0.f, acc5 = 0.f, acc6 = 0.f, acc7 = 0.f;
    for (int k = start + es; k < end; k += 16) {
        int s = csr[k];
        uint4 u = *(const uint4*)&Hs[s * DOUT + fg * 8];
        ACC8(u)
    }
#pragma unroll
    for (int m = 4; m <= 32; m <<= 1) {
        acc0 += __shfl_xor(acc0, m); acc1 += __shfl_xor(acc1, m);
        acc2 += __shfl_xor(acc2, m); acc3 += __shfl_xor(acc3, m);
        acc4 += __shfl_xor(acc4, m); acc5 += __shfl_xor(acc5, m);
        acc6 += __shfl_xor(acc6, m); acc7 += __shfl_xor(acc7, m);
    }
    float dv = dinv[node];
    uint4 su = *(const uint4*)&Hs[node * DOUT + fg * 8];
    float4 ba = *(const float4*)&b2[fg * 8];
    float4 bb = *(const float4*)&b2[fg * 8 + 4];
    float4 o0, o1;
    o0.x = fmaxf(dv * (acc0 + bflo(su.x)) + ba.x, 0.f);
    o0.y = fmaxf(dv * (acc1 + bfhi(su.x)) + ba.y, 0.f);
    o0.z = fmaxf(dv * (acc2 + bflo(su.y)) + ba.z, 0.f);
    o0.w = fmaxf(dv * (acc3 + bfhi(su.y)) + ba.w, 0.f);
    o1.x = fmaxf(dv * (acc4 + bflo(su.z)) + bb.x, 0.f);
    o1.y = fmaxf(dv * (acc5 + bfhi(su.z)) + bb.y, 0.f);
    o1.z = fmaxf(dv * (acc6 + bflo(su.w)) + bb.z, 0.f);
    o1.w = fmaxf(dv * (acc7 + bfhi(su.w)) + bb.w, 0.f);
    if (es == 0) {
        *(float4*)&h2[node * DOUT + fg * 8] = o0;
        *(float4*)&h2[node * DOUT + fg * 8 + 4] = o1;
    }
    float4 fa = *(const float4*)&fcw[fg * 8];
    float4 fb = *(const float4*)&fcw[fg * 8 + 4];
    float sv = o0.x * fa.x + o0.y * fa.y + o0.z * fa.z + o0.w * fa.w
             + o1.x * fb.x + o1.y * fb.y + o1.z * fb.z + o1.w * fb.w;
    sv += __shfl_xor(sv, 1); sv += __shfl_xor(sv, 2);
    if (lane == 0) scores[node] = sv + fcb[0];
}

extern "C" void kernel_launch(void* const* d_in, const int* in_sizes, int n_in,
                              void* d_out, int out_size, void* d_ws, size_t ws_size,
                              hipStream_t stream) {
    const float* x   = (const float*)d_in[0];
    const int*   ei  = (const int*)d_in[1];
    const float* W1  = (const float*)d_in[2];
    const float* b1  = (const float*)d_in[3];
    const float* W2  = (const float*)d_in[4];
    const float* b2  = (const float*)d_in[5];
    const float* fcw = (const float*)d_in[6];
    const float* fcb = (const float*)d_in[7];
    const int* src = ei;
    const int* dst = ei + EE;

    float* ws = (float*)d_ws;
    float* dinv    = ws;                          // NN f
    int*   offsets = (int*)(ws + NN);             // NN+1 i
    int*   bcnt    = (int*)(ws + 2 * NN + 64);    // NBUCK
    int*   bbase   = bcnt + 512;
    int*   bcur    = bbase + 512;
    int*   csr     = bcur + 512;                  // EE i
    unsigned* tmp  = (unsigned*)(csr + EE);       // EE u32
    ush*   Hs1     = (ush*)(ws + 3401600);        // NN*64 bf16
    ush*   Hs2     = (ush*)(ws + 6601600);        // NN*32 bf16
    float* h1      = ws + 8201600;                // NN*64 fp32

    float* out    = (float*)d_out;
    float* scores = out;          // NN
    float* h2     = out + NN;     // NN*32

    const int T = 256;
    // CSR build (two-pass binning)
    zero_bcnt_kernel<<<2, 256, 0, stream>>>(bcnt);
    bhist_kernel<<<NCHUNK, T, 0, stream>>>(dst, bcnt);
    bscan_kernel<<<1, T, 0, stream>>>(bcnt, bbase, bcur, offsets);
    binA_kernel<<<NCHUNK, T, 0, stream>>>(src, dst, bcur, tmp);
    binB_kernel<<<NBUCK, T, 0, stream>>>(tmp, bbase, csr, offsets, dinv);
    // layer 1: Hs1 = bf16((x@W1)*dinv)
    gemm_bf_kernel<DIN, DH><<<(NN + 63) / 64, T, 0, stream>>>(x, W1, dinv, Hs1);
    gather1_kernel<<<(NN * 64 + T - 1) / T, T, 0, stream>>>(offsets, csr, dinv, Hs1, b1, h1);
    // layer 2: Hs2 = bf16((h1@W2)*dinv)
    gemm_bf_kernel<DH, DOUT><<<(NN + 127) / 128, T, 0, stream>>>(h1, W2, dinv, Hs2);
    gather2_kernel<<<(NN * 64 + T - 1) / T, T, 0, stream>>>(offsets, csr, dinv, Hs2, b2, fcw, fcb, h2, scores);
}

// Round 9
// 261.254 us; speedup vs baseline: 1.3636x; 1.0807x over previous
//
#include <hip/hip_runtime.h>

#define NN 100000
#define EE 1600000
#define DIN 128
#define DH 64
#define DOUT 32

#define BSH 8                      // bucket = dst >> 8  (256 nodes/bucket)
#define BNODES 256
#define NBUCK ((NN + BNODES - 1) / BNODES)   // 391
#define CHUNK 4096                 // edges per Pass-A workgroup
#define NCHUNK ((EE + CHUNK - 1) / CHUNK)    // 391

typedef unsigned short ush;
typedef __attribute__((ext_vector_type(8))) short bf16x8;
typedef __attribute__((ext_vector_type(4))) float f32x4;

__device__ __forceinline__ float bflo(unsigned u) {
    union { unsigned u; float f; } c; c.u = u << 16; return c.f;
}
__device__ __forceinline__ float bfhi(unsigned u) {
    union { unsigned u; float f; } c; c.u = u & 0xffff0000u; return c.f;
}
__device__ __forceinline__ ush f2bf(float f) {
    union { float f; unsigned u; } c; c.f = f;
    unsigned r = c.u + 0x7fff + ((c.u >> 16) & 1);   // round-to-nearest-even
    return (ush)(r >> 16);
}

// ---------------- zero bucket counters ----------------
__global__ void zero_bcnt_kernel(int* __restrict__ bcnt) {
    int i = blockIdx.x * 256 + threadIdx.x;
    if (i < NBUCK) bcnt[i] = 0;
}

// ---------------- bucket histogram (LDS-first) ----------------
__global__ __launch_bounds__(256) void bhist_kernel(const int* __restrict__ dst,
                                                    int* __restrict__ bcnt) {
    __shared__ int h[NBUCK];
    int t = threadIdx.x;
    for (int i = t; i < NBUCK; i += 256) h[i] = 0;
    __syncthreads();
    int base = blockIdx.x * CHUNK;
    int end = min(base + CHUNK, EE);
    for (int i = base + t; i < end; i += 256) atomicAdd(&h[dst[i] >> BSH], 1);
    __syncthreads();
    for (int i = t; i < NBUCK; i += 256) if (h[i]) atomicAdd(&bcnt[i], h[i]);
}

// ---------------- bucket exclusive scan (1 wg) ----------------
__global__ __launch_bounds__(256) void bscan_kernel(const int* __restrict__ bcnt,
                                                    int* __restrict__ bbase,
                                                    int* __restrict__ bcur,
                                                    int* __restrict__ offsets) {
    __shared__ int s2[256];
    int t = threadIdx.x;
    int a0 = (2 * t < NBUCK) ? bcnt[2 * t] : 0;
    int a1 = (2 * t + 1 < NBUCK) ? bcnt[2 * t + 1] : 0;
    s2[t] = a0 + a1;
    __syncthreads();
    for (int off = 1; off < 256; off <<= 1) {
        int x = (t >= off) ? s2[t - off] : 0;
        __syncthreads();
        s2[t] += x;
        __syncthreads();
    }
    int excl = s2[t] - a0 - a1;
    if (2 * t < NBUCK)     { bbase[2 * t] = excl;          bcur[2 * t] = excl; }
    if (2 * t + 1 < NBUCK) { bbase[2 * t + 1] = excl + a0; bcur[2 * t + 1] = excl + a0; }
    if (t == 255) { bbase[NBUCK] = s2[255]; offsets[NN] = s2[255]; }  // = EE
}

// ---------------- Pass A: bin edges into bucket-grouped tmp (packed (src<<8)|dstlow) ----
__global__ __launch_bounds__(256) void binA_kernel(const int* __restrict__ src,
                                                   const int* __restrict__ dst,
                                                   int* __restrict__ bcur,
                                                   unsigned* __restrict__ tmp) {
    __shared__ int hist[NBUCK];
    __shared__ int scn[NBUCK + 1];
    __shared__ int cur[NBUCK];
    __shared__ int gbase[NBUCK];
    __shared__ int s2[256];
    __shared__ unsigned staged[CHUNK];
    int t = threadIdx.x;
    for (int i = t; i < NBUCK; i += 256) hist[i] = 0;
    __syncthreads();
    int e0 = blockIdx.x * CHUNK;
    int nE = min(CHUNK, EE - e0);

    int my_e[16], my_bk[16];
#pragma unroll
    for (int k = 0; k < 16; k++) {
        int li = t + k * 256;
        bool ok = li < nE;
        int idx = ok ? (e0 + li) : e0;
        int d = dst[idx];
        int s = src[idx];
        int b = d >> BSH;
        my_e[k] = (s << 8) | (d & 255);
        my_bk[k] = ok ? b : -1;
        if (ok) atomicAdd(&hist[b], 1);
    }
    __syncthreads();
    int a0 = (2 * t < NBUCK) ? hist[2 * t] : 0;
    int a1 = (2 * t + 1 < NBUCK) ? hist[2 * t + 1] : 0;
    s2[t] = a0 + a1;
    __syncthreads();
    for (int off = 1; off < 256; off <<= 1) {
        int x = (t >= off) ? s2[t - off] : 0;
        __syncthreads();
        s2[t] += x;
        __syncthreads();
    }
    int excl = s2[t] - a0 - a1;
    if (2 * t < NBUCK)     { scn[2 * t] = excl;          cur[2 * t] = excl; }
    if (2 * t + 1 < NBUCK) { scn[2 * t + 1] = excl + a0; cur[2 * t + 1] = excl + a0; }
    if (t == 0) scn[NBUCK] = nE;
    __syncthreads();
    for (int i = t; i < NBUCK; i += 256)
        gbase[i] = hist[i] ? atomicAdd(&bcur[i], hist[i]) : 0;
    __syncthreads();
#pragma unroll
    for (int k = 0; k < 16; k++) {
        if (my_bk[k] >= 0) {
            int lp = atomicAdd(&cur[my_bk[k]], 1);
            staged[lp] = (unsigned)my_e[k];
        }
    }
    __syncthreads();
    for (int i = t; i < nE; i += 256) {
        int lo = 0, hi = NBUCK;
#pragma unroll
        for (int step = 0; step < 9; step++) {
            int mid = (lo + hi) >> 1;
            bool c = scn[mid] <= i;
            lo = c ? mid : lo;
            hi = c ? hi : mid;
        }
        tmp[gbase[lo] + (i - scn[lo])] = staged[i];
    }
}

// ---------------- Pass B: per-bucket node histogram + scan -> offsets/dinv/csr ----------
__global__ __launch_bounds__(256) void binB_kernel(const unsigned* __restrict__ tmp,
                                                   const int* __restrict__ bbase,
                                                   int* __restrict__ csr,
                                                   int* __restrict__ offsets,
                                                   float* __restrict__ dinv) {
    __shared__ int hist[BNODES], cur[BNODES], sc[BNODES];
    int b = blockIdx.x, t = threadIdx.x;
    int e0 = bbase[b], e1 = bbase[b + 1];
    hist[t] = 0;
    __syncthreads();
    for (int i = e0 + t; i < e1; i += 256) atomicAdd(&hist[tmp[i] & 255], 1);
    __syncthreads();
    int v = hist[t];
    sc[t] = v;
    __syncthreads();
    for (int off = 1; off < 256; off <<= 1) {
        int x = (t >= off) ? sc[t - off] : 0;
        __syncthreads();
        sc[t] += x;
        __syncthreads();
    }
    int excl = sc[t] - v;
    cur[t] = e0 + excl;
    int node = (b << BSH) + t;
    if (node < NN) {
        offsets[node] = e0 + excl;
        dinv[node] = 1.0f / sqrtf((float)v + 1.0f);
    }
    __syncthreads();
    for (int i = e0 + t; i < e1; i += 256) {
        unsigned u = tmp[i];
        int pos = atomicAdd(&cur[u & 255], 1);
        csr[pos] = (int)(u >> 8);
    }
}

// ---------------- MFMA GEMM + dinv-scale, bf16 out: Y = bf16((X@W)*dinv) -------------
// 128 rows/block, 4 waves x 32 rows. X (fp32) -> bf16 LDS [row][k], padded stride;
// W -> bf16 LDS transposed [n][k]. mfma_f32_16x16x32_bf16.
// Verified layouts: A[m=lane&15][k=quad*8+j]; B[n=lane&15][k=quad*8+j];
// C/D col=lane&15, row=quad*4+reg.
template <int K, int NC>
__global__ __launch_bounds__(256) void gemm_mfma_kernel(const float* __restrict__ X,
                                                        const float* __restrict__ W,
                                                        const float* __restrict__ dinv,
                                                        ush* __restrict__ Y) {
    constexpr int GROWS = 128;
    constexpr int KP = K + 8;            // pad: row stride odd multiple of 16B
    constexpr int NKC = K / 32;          // k-chunks
    constexpr int NCT = NC / 16;         // col tiles
    __shared__ __align__(16) ush Xl[GROWS * KP];
    __shared__ __align__(16) ush Wt[NC * KP];
    const int t = threadIdx.x;
    const int row0 = blockIdx.x * GROWS;

    // stage X -> bf16 (guarded)
    for (int i = t; i < GROWS * (K / 4); i += 256) {
        int r = i / (K / 4), c4 = i % (K / 4);
        int row = row0 + r;
        float4 v = make_float4(0.f, 0.f, 0.f, 0.f);
        if (row < NN) v = *(const float4*)&X[(size_t)row * K + c4 * 4];
        ushort4 o;
        o.x = f2bf(v.x); o.y = f2bf(v.y); o.z = f2bf(v.z); o.w = f2bf(v.w);
        *(ushort4*)&Xl[r * KP + c4 * 4] = o;
    }
    // stage W transposed -> bf16
    for (int i = t; i < K * (NC / 4); i += 256) {
        int k = i / (NC / 4), n4 = i % (NC / 4);
        float4 v = *(const float4*)&W[k * NC + n4 * 4];
        Wt[(n4 * 4 + 0) * KP + k] = f2bf(v.x);
        Wt[(n4 * 4 + 1) * KP + k] = f2bf(v.y);
        Wt[(n4 * 4 + 2) * KP + k] = f2bf(v.z);
        Wt[(n4 * 4 + 3) * KP + k] = f2bf(v.w);
    }
    __syncthreads();

    const int wave = t >> 6, lane = t & 63;
    const int m = lane & 15, quad = lane >> 4;
    const int wrow = wave * 32;

    f32x4 acc[2][NCT];
#pragma unroll
    for (int rt = 0; rt < 2; rt++)
#pragma unroll
        for (int ct = 0; ct < NCT; ct++) acc[rt][ct] = (f32x4){0.f, 0.f, 0.f, 0.f};

#pragma unroll
    for (int kc = 0; kc < NKC; kc++) {
        int koff = kc * 32 + quad * 8;
        bf16x8 b[NCT];
#pragma unroll
        for (int ct = 0; ct < NCT; ct++)
            b[ct] = *(const bf16x8*)&Wt[(ct * 16 + m) * KP + koff];
#pragma unroll
        for (int rt = 0; rt < 2; rt++) {
            bf16x8 a = *(const bf16x8*)&Xl[(wrow + rt * 16 + m) * KP + koff];
#pragma unroll
            for (int ct = 0; ct < NCT; ct++)
                acc[rt][ct] = __builtin_amdgcn_mfma_f32_16x16x32_bf16(a, b[ct], acc[rt][ct], 0, 0, 0);
        }
    }
    // epilogue: scale by dinv, store bf16
#pragma unroll
    for (int rt = 0; rt < 2; rt++) {
#pragma unroll
        for (int reg = 0; reg < 4; reg++) {
            int row = row0 + wrow + rt * 16 + quad * 4 + reg;
            if (row < NN) {
                float s = dinv[row];
#pragma unroll
                for (int ct = 0; ct < NCT; ct++)
                    Y[(size_t)row * NC + ct * 16 + m] = f2bf(acc[rt][ct][reg] * s);
            }
        }
    }
}

#define ACC8(u4)                                      \
    acc0 += bflo(u4.x); acc1 += bfhi(u4.x);           \
    acc2 += bflo(u4.y); acc3 += bfhi(u4.y);           \
    acc4 += bflo(u4.z); acc5 += bfhi(u4.z);           \
    acc6 += bflo(u4.w); acc7 += bfhi(u4.w);

// ---------------- gather1 (F=64 bf16): wave/node, 8 edge-slots x 8 fgroups, uint4 loads -
// h1 = relu(dv*(sum Hs1[s] + Hs1[node]) + b1), written bf16 (feeds MFMA gemm2)
__global__ __launch_bounds__(256) void gather1_kernel(const int* __restrict__ offsets,
                                                      const int* __restrict__ csr,
                                                      const float* __restrict__ dinv,
                                                      const ush* __restrict__ Hs,
                                                      const float* __restrict__ b1,
                                                      float* __restrict__ h1) {
    int node = (blockIdx.x * 256 + threadIdx.x) >> 6;
    int lane = threadIdx.x & 63;
    if (node >= NN) return;
    int fg = lane & 7, es = lane >> 3;     // 8 fgroups x 8 bf16, 8 edge slots
    int start = offsets[node], end = offsets[node + 1];
    float acc0 = 0.f, acc1 = 0.f, acc2 = 0.f, acc3 = 0.f;
    float acc4 = 0.f, acc5 = 0.f, acc6 = 0.f, acc7 = 0.f;
    int k = start + es;
    for (; k + 8 < end; k += 16) {         // 2 rows in flight per lane (16 per wave)
        int s0 = csr[k], s1 = csr[k + 8];
        uint4 u0 = *(const uint4*)&Hs[s0 * DH + fg * 8];
        uint4 u1 = *(const uint4*)&Hs[s1 * DH + fg * 8];
        ACC8(u0) ACC8(u1)
    }
    if (k < end) {
        int s = csr[k];
        uint4 u = *(const uint4*)&Hs[s * DH + fg * 8];
        ACC8(u)
    }
#pragma unroll
    for (int m = 8; m <= 32; m <<= 1) {
        acc0 += __shfl_xor(acc0, m); acc1 += __shfl_xor(acc1, m);
        acc2 += __shfl_xor(acc2, m); acc3 += __shfl_xor(acc3, m);
        acc4 += __shfl_xor(acc4, m); acc5 += __shfl_xor(acc5, m);
        acc6 += __shfl_xor(acc6, m); acc7 += __shfl_xor(acc7, m);
    }
    float dv = dinv[node];
    uint4 su = *(const uint4*)&Hs[node * DH + fg * 8];
    float4 ba = *(const float4*)&b1[fg * 8];
    float4 bb = *(const float4*)&b1[fg * 8 + 4];
    float4 o0, o1;
    o0.x = fmaxf(dv * (acc0 + bflo(su.x)) + ba.x, 0.f);
    o0.y = fmaxf(dv * (acc1 + bfhi(su.x)) + ba.y, 0.f);
    o0.z = fmaxf(dv * (acc2 + bflo(su.y)) + ba.z, 0.f);
    o0.w = fmaxf(dv * (acc3 + bfhi(su.y)) + ba.w, 0.f);
    o1.x = fmaxf(dv * (acc4 + bflo(su.z)) + bb.x, 0.f);
    o1.y = fmaxf(dv * (acc5 + bfhi(su.z)) + bb.y, 0.f);
    o1.z = fmaxf(dv * (acc6 + bflo(su.w)) + bb.z, 0.f);
    o1.w = fmaxf(dv * (acc7 + bfhi(su.w)) + bb.w, 0.f);
    if (es == 0) {
        *(float4*)&h1[node * DH + fg * 8] = o0;
        *(float4*)&h1[node * DH + fg * 8 + 4] = o1;
    }
}

// ---------------- gather2 (F=32 bf16): wave/node, 16 edge-slots x 4 fgroups + fc -------
__global__ __launch_bounds__(256) void gather2_kernel(const int* __restrict__ offsets,
                                                      const int* __restrict__ csr,
                                                      const float* __restrict__ dinv,
                                                      const ush* __restrict__ Hs,
                                                      const float* __restrict__ b2,
                                                      const float* __restrict__ fcw,
                                                      const float* __restrict__ fcb,
                                                      float* __restrict__ h2,
                                                      float* __restrict__ scores) {
    int node = (blockIdx.x * 256 + threadIdx.x) >> 6;
    int lane = threadIdx.x & 63;
    if (node >= NN) return;
    int fg = lane & 3, es = lane >> 2;     // 4 fgroups x 8 bf16, 16 edge slots
    int start = offsets[node], end = offsets[node + 1];
    float acc0 = 0.f, acc1 = 0.f, acc2 = 0.f, acc3 = 0.f;
    float acc4 = 0.f, acc5 = 0.f, acc6 = 0.f, acc7 = 0.f;
    for (int k = start + es; k < end; k += 16) {
        int s = csr[k];
        uint4 u = *(const uint4*)&Hs[s * DOUT + fg * 8];
        ACC8(u)
    }
#pragma unroll
    for (int m = 4; m <= 32; m <<= 1) {
        acc0 += __shfl_xor(acc0, m); acc1 += __shfl_xor(acc1, m);
        acc2 += __shfl_xor(acc2, m); acc3 += __shfl_xor(acc3, m);
        acc4 += __shfl_xor(acc4, m); acc5 += __shfl_xor(acc5, m);
        acc6 += __shfl_xor(acc6, m); acc7 += __shfl_xor(acc7, m);
    }
    float dv = dinv[node];
    uint4 su = *(const uint4*)&Hs[node * DOUT + fg * 8];
    float4 ba = *(const float4*)&b2[fg * 8];
    float4 bb = *(const float4*)&b2[fg * 8 + 4];
    float4 o0, o1;
    o0.x = fmaxf(dv * (acc0 + bflo(su.x)) + ba.x, 0.f);
    o0.y = fmaxf(dv * (acc1 + bfhi(su.x)) + ba.y, 0.f);
    o0.z = fmaxf(dv * (acc2 + bflo(su.y)) + ba.z, 0.f);
    o0.w = fmaxf(dv * (acc3 + bfhi(su.y)) + ba.w, 0.f);
    o1.x = fmaxf(dv * (acc4 + bflo(su.z)) + bb.x, 0.f);
    o1.y = fmaxf(dv * (acc5 + bfhi(su.z)) + bb.y, 0.f);
    o1.z = fmaxf(dv * (acc6 + bflo(su.w)) + bb.z, 0.f);
    o1.w = fmaxf(dv * (acc7 + bfhi(su.w)) + bb.w, 0.f);
    if (es == 0) {
        *(float4*)&h2[node * DOUT + fg * 8] = o0;
        *(float4*)&h2[node * DOUT + fg * 8 + 4] = o1;
    }
    float4 fa = *(const float4*)&fcw[fg * 8];
    float4 fb = *(const float4*)&fcw[fg * 8 + 4];
    float sv = o0.x * fa.x + o0.y * fa.y + o0.z * fa.z + o0.w * fa.w
             + o1.x * fb.x + o1.y * fb.y + o1.z * fb.z + o1.w * fb.w;
    sv += __shfl_xor(sv, 1); sv += __shfl_xor(sv, 2);
    if (lane == 0) scores[node] = sv + fcb[0];
}

extern "C" void kernel_launch(void* const* d_in, const int* in_sizes, int n_in,
                              void* d_out, int out_size, void* d_ws, size_t ws_size,
                              hipStream_t stream) {
    const float* x   = (const float*)d_in[0];
    const int*   ei  = (const int*)d_in[1];
    const float* W1  = (const float*)d_in[2];
    const float* b1  = (const float*)d_in[3];
    const float* W2  = (const float*)d_in[4];
    const float* b2  = (const float*)d_in[5];
    const float* fcw = (const float*)d_in[6];
    const float* fcb = (const float*)d_in[7];
    const int* src = ei;
    const int* dst = ei + EE;

    float* ws = (float*)d_ws;
    float* dinv    = ws;                          // NN f
    int*   offsets = (int*)(ws + NN);             // NN+1 i
    int*   bcnt    = (int*)(ws + 2 * NN + 64);    // NBUCK
    int*   bbase   = bcnt + 512;
    int*   bcur    = bbase + 512;
    int*   csr     = bcur + 512;                  // EE i
    unsigned* tmp  = (unsigned*)(csr + EE);       // EE u32
    ush*   Hs1     = (ush*)(ws + 3401600);        // NN*64 bf16
    ush*   Hs2     = (ush*)(ws + 6601600);        // NN*32 bf16
    float* h1      = ws + 8201600;                // NN*64 fp32

    float* out    = (float*)d_out;
    float* scores = out;          // NN
    float* h2     = out + NN;     // NN*32

    const int T = 256;
    // CSR build (two-pass binning)
    zero_bcnt_kernel<<<2, 256, 0, stream>>>(bcnt);
    bhist_kernel<<<NCHUNK, T, 0, stream>>>(dst, bcnt);
    bscan_kernel<<<1, T, 0, stream>>>(bcnt, bbase, bcur, offsets);
    binA_kernel<<<NCHUNK, T, 0, stream>>>(src, dst, bcur, tmp);
    binB_kernel<<<NBUCK, T, 0, stream>>>(tmp, bbase, csr, offsets, dinv);
    // layer 1: Hs1 = bf16((x@W1)*dinv)   [MFMA]
    gemm_mfma_kernel<DIN, DH><<<(NN + 127) / 128, T, 0, stream>>>(x, W1, dinv, Hs1);
    gather1_kernel<<<(NN * 64 + T - 1) / T, T, 0, stream>>>(offsets, csr, dinv, Hs1, b1, h1);
    // layer 2: Hs2 = bf16((h1@W2)*dinv)  [MFMA]
    gemm_mfma_kernel<DH, DOUT><<<(NN + 127) / 128, T, 0, stream>>>(h1, W2, dinv, Hs2);
    gather2_kernel<<<(NN * 64 + T - 1) / T, T, 0, stream>>>(offsets, csr, dinv, Hs2, b2, fcw, fcb, h2, scores);
}